// Round 1
// baseline (331.132 us; speedup 1.0000x reference)
//
#include <hip/hip_runtime.h>
#include <math.h>

// Sizes (fixed by the problem)
#define B_SZ 8
#define T_LEN 4096
#define D_IN 128
#define D_OUT 128
#define N_ST 256
#define BT (B_SZ * T_LEN)        // 32768
#define CHUNK 64                  // scan chunk length L
#define NCHUNK (T_LEN / CHUNK)    // 64 chunks per sequence

// ---------------------------------------------------------------------------
// K0a: per-state params + lambda-power table lampow[j][n] = lam^j, j=0..CHUNK
// ---------------------------------------------------------------------------
__global__ __launch_bounds__(256) void k0_params(
    const float* __restrict__ nu_log, const float* __restrict__ theta_log,
    float* __restrict__ lampow_re, float* __restrict__ lampow_im) {
  int n = threadIdx.x;
  float e_nu = expf(nu_log[n]);     // so lam_abs = exp(-e_nu)
  float phase = expf(theta_log[n]);
  for (int j = 0; j <= CHUNK; ++j) {
    float r = expf(-(float)j * e_nu);
    float a = (float)j * phase;
    lampow_re[j * N_ST + n] = r * cosf(a);
    lampow_im[j * N_ST + n] = r * sinf(a);
  }
}

// ---------------------------------------------------------------------------
// K0b: transpose weights (fold gamma into B): gBt[k][n], Ct[n][d], Dt[k][d]
// ---------------------------------------------------------------------------
__global__ __launch_bounds__(256) void k0_trans(
    const float* __restrict__ gamma_log,
    const float* __restrict__ B_re, const float* __restrict__ B_im,
    const float* __restrict__ C_re, const float* __restrict__ C_im,
    const float* __restrict__ Dm,
    float* __restrict__ gBt_re, float* __restrict__ gBt_im,
    float* __restrict__ Ct_re, float* __restrict__ Ct_im,
    float* __restrict__ Dt) {
  int idx = blockIdx.x * 256 + threadIdx.x;
  if (idx < N_ST * D_IN) {  // 32768
    int n = idx >> 7, k = idx & 127;       // B is [N][D_IN]
    float g = expf(gamma_log[n]);
    gBt_re[k * N_ST + n] = g * B_re[idx];
    gBt_im[k * N_ST + n] = g * B_im[idx];
    int d = idx >> 8, nn = idx & 255;      // C is [D_OUT][N]
    Ct_re[nn * D_OUT + d] = C_re[idx];
    Ct_im[nn * D_OUT + d] = C_im[idx];
  }
  if (idx < D_OUT * D_IN) {                // D is [D_OUT][D_IN]
    int d = idx >> 7, k = idx & 127;
    Dt[k * D_OUT + d] = Dm[idx];
  }
}

// ---------------------------------------------------------------------------
// K1: Bu = x @ (gamma*B)^T   -> Bu_re/Bu_im [BT][N]
// Block: 256 threads (one per n), 16 time rows; x tile in LDS (broadcast reads)
// ---------------------------------------------------------------------------
#define K1_ROWS 16
__global__ __launch_bounds__(256) void k1_gemm1(
    const float* __restrict__ x,
    const float* __restrict__ gBt_re, const float* __restrict__ gBt_im,
    float* __restrict__ Bu_re, float* __restrict__ Bu_im) {
  __shared__ __attribute__((aligned(16))) float xs[K1_ROWS * D_IN];
  int row0 = blockIdx.x * K1_ROWS;
  const float4* xg = (const float4*)(x + (size_t)row0 * D_IN);
  float4* xs4 = (float4*)xs;
  for (int i = threadIdx.x; i < K1_ROWS * D_IN / 4; i += 256) xs4[i] = xg[i];
  __syncthreads();

  int n = threadIdx.x;
  float accr[K1_ROWS], acci[K1_ROWS];
#pragma unroll
  for (int t = 0; t < K1_ROWS; ++t) { accr[t] = 0.f; acci[t] = 0.f; }

  for (int k4 = 0; k4 < D_IN / 4; ++k4) {
    float br[4], bi[4];
#pragma unroll
    for (int j = 0; j < 4; ++j) {
      br[j] = gBt_re[(k4 * 4 + j) * N_ST + n];
      bi[j] = gBt_im[(k4 * 4 + j) * N_ST + n];
    }
#pragma unroll
    for (int t = 0; t < K1_ROWS; ++t) {
      float4 xv = ((const float4*)(xs + t * D_IN))[k4];
      accr[t] += xv.x * br[0] + xv.y * br[1] + xv.z * br[2] + xv.w * br[3];
      acci[t] += xv.x * bi[0] + xv.y * bi[1] + xv.z * bi[2] + xv.w * bi[3];
    }
  }
#pragma unroll
  for (int t = 0; t < K1_ROWS; ++t) {
    size_t o = (size_t)(row0 + t) * N_ST + n;
    Bu_re[o] = accr[t];
    Bu_im[o] = acci[t];
  }
}

// ---------------------------------------------------------------------------
// K2a: local (zero-init) scan within each chunk, in place on Bu.
// Thread = (b, chunk, n). Note global bt index = bc*CHUNK + j (contiguous).
// Writes chunk-final state E[bc][n].
// ---------------------------------------------------------------------------
__global__ __launch_bounds__(256) void k2_scan(
    float* __restrict__ Bu_re, float* __restrict__ Bu_im,
    const float* __restrict__ lampow_re, const float* __restrict__ lampow_im,
    float* __restrict__ E_re, float* __restrict__ E_im) {
  int g = blockIdx.x * 256 + threadIdx.x;  // 0 .. B*NCHUNK*N-1 = 131071
  int n = g & (N_ST - 1);
  int bc = g >> 8;                         // b*NCHUNK + c
  float lre = lampow_re[1 * N_ST + n];     // lam^1
  float lim = lampow_im[1 * N_ST + n];
  float sre = 0.f, sim = 0.f;
  size_t idx = (size_t)bc * CHUNK * N_ST + n;
  for (int j = 0; j < CHUNK; ++j) {
    float br = Bu_re[idx], bi = Bu_im[idx];
    float nr = fmaf(lre, sre, fmaf(-lim, sim, br));
    float ni = fmaf(lre, sim, fmaf(lim, sre, bi));
    sre = nr; sim = ni;
    Bu_re[idx] = sre; Bu_im[idx] = sim;
    idx += N_ST;
  }
  E_re[g] = sre;
  E_im[g] = sim;
}

// ---------------------------------------------------------------------------
// K2b: carry scan across chunks per (b,n): P[c] = true state at end of chunk
// c-1 (P[0]=0); carry' = E[c] + lam^CHUNK * carry.
// ---------------------------------------------------------------------------
__global__ __launch_bounds__(256) void k2_carry(
    const float* __restrict__ E_re, const float* __restrict__ E_im,
    const float* __restrict__ lampow_re, const float* __restrict__ lampow_im,
    float* __restrict__ P_re, float* __restrict__ P_im) {
  int g = blockIdx.x * 256 + threadIdx.x;  // 0..2047  (b*N + n)
  int n = g & (N_ST - 1);
  int b = g >> 8;
  float lLre = lampow_re[CHUNK * N_ST + n];
  float lLim = lampow_im[CHUNK * N_ST + n];
  float cre = 0.f, cim = 0.f;
  for (int c = 0; c < NCHUNK; ++c) {
    int i = (b * NCHUNK + c) * N_ST + n;
    P_re[i] = cre; P_im[i] = cim;
    float er = E_re[i], ei = E_im[i];
    float nre = fmaf(lLre, cre, fmaf(-lLim, cim, er));
    float nim = fmaf(lLre, cim, fmaf(lLim, cre, ei));
    cre = nre; cim = nim;
  }
}

// ---------------------------------------------------------------------------
// K3: y = Re(states @ C^T) + x @ D^T, with carry fix-up fused into the
// LDS-load of the state tile: s_true = s_loc + lam^{j+1} * P[b][c].
// Block: 256 threads, 16 time rows; thread -> d = tid&127, row-half = tid>>7.
// ---------------------------------------------------------------------------
#define K3_ROWS 16
__global__ __launch_bounds__(256) void k3_out(
    const float* __restrict__ x,
    const float* __restrict__ Bu_re, const float* __restrict__ Bu_im,
    const float* __restrict__ P_re, const float* __restrict__ P_im,
    const float* __restrict__ lampow_re, const float* __restrict__ lampow_im,
    const float* __restrict__ Ct_re, const float* __restrict__ Ct_im,
    const float* __restrict__ Dt,
    float* __restrict__ y) {
  __shared__ __attribute__((aligned(16))) float sre[K3_ROWS * N_ST];
  __shared__ __attribute__((aligned(16))) float sim_[K3_ROWS * N_ST];
  __shared__ __attribute__((aligned(16))) float xs[K3_ROWS * D_IN];

  int row0 = blockIdx.x * K3_ROWS;       // global bt
  int pbase = (row0 >> 6) * N_ST;        // (b*NCHUNK + c) * N  (rows share chunk)

  // load + correct state tile
  for (int i = threadIdx.x; i < K3_ROWS * N_ST; i += 256) {
    int r = i >> 8, n = i & 255;
    int j = (row0 + r) & (CHUNK - 1);
    size_t gi = (size_t)(row0 + r) * N_ST + n;
    float lre = lampow_re[(j + 1) * N_ST + n];
    float lim = lampow_im[(j + 1) * N_ST + n];
    float pre = P_re[pbase + n], pim = P_im[pbase + n];
    sre[i] = Bu_re[gi] + lre * pre - lim * pim;
    sim_[i] = Bu_im[gi] + lre * pim + lim * pre;
  }
  // x tile (contiguous rows)
  const float4* xg = (const float4*)(x + (size_t)row0 * D_IN);
  float4* xs4 = (float4*)xs;
  for (int i = threadIdx.x; i < K3_ROWS * D_IN / 4; i += 256) xs4[i] = xg[i];
  __syncthreads();

  int d = threadIdx.x & 127;
  int rh = (threadIdx.x >> 7) * 8;       // 0 or 8 (8 rows per thread)
  float acc[8];
#pragma unroll
  for (int r = 0; r < 8; ++r) acc[r] = 0.f;

  for (int n4 = 0; n4 < N_ST / 4; ++n4) {
    float cr[4], ci[4];
#pragma unroll
    for (int j = 0; j < 4; ++j) {
      cr[j] = Ct_re[(n4 * 4 + j) * D_OUT + d];
      ci[j] = Ct_im[(n4 * 4 + j) * D_OUT + d];
    }
#pragma unroll
    for (int r = 0; r < 8; ++r) {
      float4 s4 = ((const float4*)(sre + (rh + r) * N_ST))[n4];
      float4 i4 = ((const float4*)(sim_ + (rh + r) * N_ST))[n4];
      acc[r] += s4.x * cr[0] + s4.y * cr[1] + s4.z * cr[2] + s4.w * cr[3];
      acc[r] -= i4.x * ci[0] + i4.y * ci[1] + i4.z * ci[2] + i4.w * ci[3];
    }
  }
  for (int k4 = 0; k4 < D_IN / 4; ++k4) {
    float dv[4];
#pragma unroll
    for (int j = 0; j < 4; ++j) dv[j] = Dt[(k4 * 4 + j) * D_OUT + d];
#pragma unroll
    for (int r = 0; r < 8; ++r) {
      float4 xv = ((const float4*)(xs + (rh + r) * D_IN))[k4];
      acc[r] += xv.x * dv[0] + xv.y * dv[1] + xv.z * dv[2] + xv.w * dv[3];
    }
  }
#pragma unroll
  for (int r = 0; r < 8; ++r) {
    y[(size_t)(row0 + rh + r) * D_OUT + d] = acc[r];
  }
}

// ---------------------------------------------------------------------------
extern "C" void kernel_launch(void* const* d_in, const int* in_sizes, int n_in,
                              void* d_out, int out_size, void* d_ws, size_t ws_size,
                              hipStream_t stream) {
  const float* x         = (const float*)d_in[0];
  const float* nu_log    = (const float*)d_in[1];
  const float* theta_log = (const float*)d_in[2];
  const float* gamma_log = (const float*)d_in[3];
  const float* B_re      = (const float*)d_in[4];
  const float* B_im      = (const float*)d_in[5];
  const float* C_re      = (const float*)d_in[6];
  const float* C_im      = (const float*)d_in[7];
  const float* Dm        = (const float*)d_in[8];
  float* y = (float*)d_out;

  // workspace layout (floats)
  float* w = (float*)d_ws;
  float* lampow_re = w; w += (CHUNK + 1) * N_ST;
  float* lampow_im = w; w += (CHUNK + 1) * N_ST;
  float* gBt_re = w; w += D_IN * N_ST;
  float* gBt_im = w; w += D_IN * N_ST;
  float* Ct_re  = w; w += N_ST * D_OUT;
  float* Ct_im  = w; w += N_ST * D_OUT;
  float* Dt     = w; w += D_IN * D_OUT;
  float* E_re   = w; w += B_SZ * NCHUNK * N_ST;
  float* E_im   = w; w += B_SZ * NCHUNK * N_ST;
  float* P_re   = w; w += B_SZ * NCHUNK * N_ST;
  float* P_im   = w; w += B_SZ * NCHUNK * N_ST;
  float* Bu_re  = w; w += (size_t)BT * N_ST;
  float* Bu_im  = w; w += (size_t)BT * N_ST;

  hipLaunchKernelGGL(k0_params, dim3(1), dim3(256), 0, stream,
                     nu_log, theta_log, lampow_re, lampow_im);
  hipLaunchKernelGGL(k0_trans, dim3(128), dim3(256), 0, stream,
                     gamma_log, B_re, B_im, C_re, C_im, Dm,
                     gBt_re, gBt_im, Ct_re, Ct_im, Dt);
  hipLaunchKernelGGL(k1_gemm1, dim3(BT / K1_ROWS), dim3(256), 0, stream,
                     x, gBt_re, gBt_im, Bu_re, Bu_im);
  hipLaunchKernelGGL(k2_scan, dim3(B_SZ * NCHUNK * N_ST / 256), dim3(256), 0, stream,
                     Bu_re, Bu_im, lampow_re, lampow_im, E_re, E_im);
  hipLaunchKernelGGL(k2_carry, dim3(B_SZ * N_ST / 256), dim3(256), 0, stream,
                     E_re, E_im, lampow_re, lampow_im, P_re, P_im);
  hipLaunchKernelGGL(k3_out, dim3(BT / K3_ROWS), dim3(256), 0, stream,
                     x, Bu_re, Bu_im, P_re, P_im, lampow_re, lampow_im,
                     Ct_re, Ct_im, Dt, y);
}

// Round 2
// 155.742 us; speedup vs baseline: 2.1262x; 2.1262x over previous
//
#include <hip/hip_runtime.h>
#include <math.h>

// Sizes (fixed by the problem)
#define B_SZ 8
#define T_LEN 4096
#define D_IN 128
#define D_OUT 128
#define N_ST 256
#define BT (B_SZ * T_LEN)        // 32768
#define CHUNK 64                 // scan chunk length
#define NCHUNK (T_LEN / CHUNK)   // 64 chunks per sequence
#define NBLK (B_SZ * NCHUNK)     // 512 chunk-blocks

typedef __attribute__((ext_vector_type(8))) short short8;
typedef __attribute__((ext_vector_type(4))) float f32x4;
typedef unsigned int uint;
typedef unsigned short ushort;

static __device__ __forceinline__ short f2bf(float f) {
  union { float f; uint u; } v; v.f = f;
  uint r = v.u + 0x7FFFu + ((v.u >> 16) & 1u);  // round-to-nearest-even
  return (short)(r >> 16);
}
static __device__ __forceinline__ float bf2f(uint h) {
  union { uint u; float f; } v; v.u = h << 16;
  return v.f;
}
static __device__ __forceinline__ uint pack2(float a, float b) {
  return (uint)(ushort)f2bf(a) | ((uint)(ushort)f2bf(b) << 16);
}

// ---------------------------------------------------------------------------
// K0a: lambda-power table lampow2[j*256+n] = (re,im) of lam^j, j=0..CHUNK
// ---------------------------------------------------------------------------
__global__ __launch_bounds__(256) void k0_params(
    const float* __restrict__ nu_log, const float* __restrict__ theta_log,
    float2* __restrict__ lampow2) {
  int n = threadIdx.x;
  float e_nu = expf(nu_log[n]);
  float phase = expf(theta_log[n]);
  for (int j = 0; j <= CHUNK; ++j) {
    float r = expf(-(float)j * e_nu);
    float a = (float)j * phase;
    float2 v; v.x = r * cosf(a); v.y = r * sinf(a);
    lampow2[j * N_ST + n] = v;
  }
}

// ---------------------------------------------------------------------------
// K0b: pre-pack weights into MFMA B-fragment order (bf16).
// Wf1[kg][col][j] = W1[kg*8+j][col],  kg<16, col<512 (col=2n re, 2n+1 im)
//   W1[k][2n]=gamma_n*B_re[n][k], W1[k][2n+1]=gamma_n*B_im[n][k]
// Wf2[kg][d][j]  = W2[kg*8+j][d],   kg<80, d<128
//   W2[2n][d]=C_re[d][n], W2[2n+1][d]=-C_im[d][n], W2[512+kx][d]=D[d][kx]
// ---------------------------------------------------------------------------
__global__ __launch_bounds__(256) void k0_packW(
    const float* __restrict__ gamma_log,
    const float* __restrict__ B_re, const float* __restrict__ B_im,
    const float* __restrict__ C_re, const float* __restrict__ C_im,
    const float* __restrict__ Dm,
    short* __restrict__ Wf1, short* __restrict__ Wf2) {
  int idx = blockIdx.x * 256 + threadIdx.x;
  if (idx < 16 * 512 * 8) {
    int j = idx & 7, col = (idx >> 3) & 511, kg = idx >> 12;
    int k = kg * 8 + j;
    int n = col >> 1, ri = col & 1;
    float g = expf(gamma_log[n]);
    float v = g * (ri ? B_im[n * D_IN + k] : B_re[n * D_IN + k]);
    Wf1[idx] = f2bf(v);
  }
  if (idx < 80 * 128 * 8) {
    int j = idx & 7, d = (idx >> 3) & 127, kg = idx >> 10;
    int k = kg * 8 + j;
    float v;
    if (k < 512) {
      int n = k >> 1;
      v = (k & 1) ? -C_im[d * N_ST + n] : C_re[d * N_ST + n];
    } else {
      v = Dm[d * D_IN + (k - 512)];
    }
    Wf2[idx] = f2bf(v);
  }
}

// ---------------------------------------------------------------------------
// kA: fused GEMM1 (bf16 MFMA) + local chunk scan.
// Block = one (b,chunk): 64 time rows x 256 states. 4 waves.
// MFMA: Bu[64][512] = x_bf[64][128] @ W1[128][512], accum fp32, -> LDS bf16.
// Scan: thread n scans 64 steps, writes packed bf16 states + carry E.
// ---------------------------------------------------------------------------
__global__ __launch_bounds__(256, 2) void kA(
    const float* __restrict__ x, const short* __restrict__ Wf1,
    const float2* __restrict__ lampow2,
    uint* __restrict__ states, float2* __restrict__ E) {
  __shared__ short bu[64 * 520];   // row-major, +8 pad per row

  int bc = blockIdx.x;
  size_t row0 = (size_t)bc * CHUNK;
  int tid = threadIdx.x;
  int lane = tid & 63, w = tid >> 6;
  int m = lane & 15, q = lane >> 4;

  f32x4 acc[32];
#pragma unroll
  for (int ct = 0; ct < 32; ++ct) acc[ct] = (f32x4){0.f, 0.f, 0.f, 0.f};

  const float* xrow = x + (row0 + 16 * w + m) * D_IN;

  for (int ks = 0; ks < 4; ++ks) {
    float4 xa = *(const float4*)(xrow + 32 * ks + 8 * q);
    float4 xb = *(const float4*)(xrow + 32 * ks + 8 * q + 4);
    short8 af;
    af[0] = f2bf(xa.x); af[1] = f2bf(xa.y); af[2] = f2bf(xa.z); af[3] = f2bf(xa.w);
    af[4] = f2bf(xb.x); af[5] = f2bf(xb.y); af[6] = f2bf(xb.z); af[7] = f2bf(xb.w);
    const short* wbase = Wf1 + ((size_t)(4 * ks + q) * 512 + m) * 8;
#pragma unroll
    for (int ct = 0; ct < 32; ++ct) {
      short8 bf = *(const short8*)(wbase + 16 * ct * 8);
      acc[ct] = __builtin_amdgcn_mfma_f32_16x16x32_bf16(af, bf, acc[ct], 0, 0, 0);
    }
  }

  // write Bu tile to LDS (bf16). C-layout: row=4q+r, col=m within 16x16 tile.
#pragma unroll
  for (int ct = 0; ct < 32; ++ct) {
#pragma unroll
    for (int r = 0; r < 4; ++r) {
      bu[(16 * w + 4 * q + r) * 520 + 16 * ct + m] = f2bf(acc[ct][r]);
    }
  }
  __syncthreads();

  // scan: thread n owns state n
  int n = tid;
  float2 lam = lampow2[N_ST + n];  // lam^1
  float sre = 0.f, sim = 0.f;
  uint* sg = states + row0 * N_ST + n;
  for (int j = 0; j < CHUNK; ++j) {
    uint p = ((const uint*)(bu + j * 520))[n];
    float br = bf2f(p & 0xffffu), bi = bf2f(p >> 16);
    float nr = fmaf(lam.x, sre, fmaf(-lam.y, sim, br));
    float ni = fmaf(lam.x, sim, fmaf(lam.y, sre, bi));
    sre = nr; sim = ni;
    sg[(size_t)j * N_ST] = pack2(sre, sim);
  }
  float2 e; e.x = sre; e.y = sim;
  E[bc * N_ST + n] = e;
}

// ---------------------------------------------------------------------------
// kB: carry scan across chunks per (b,n). P[c] = state at end of chunk c-1.
// ---------------------------------------------------------------------------
__global__ __launch_bounds__(256) void kB(
    const float2* __restrict__ E, const float2* __restrict__ lampow2,
    float2* __restrict__ P) {
  int g = blockIdx.x * 256 + threadIdx.x;  // b*N + n
  int n = g & (N_ST - 1);
  int b = g >> 8;
  float2 lamL = lampow2[CHUNK * N_ST + n];
  float cre = 0.f, cim = 0.f;
  for (int c = 0; c < NCHUNK; ++c) {
    int i = (b * NCHUNK + c) * N_ST + n;
    float2 pv; pv.x = cre; pv.y = cim;
    P[i] = pv;
    float2 e = E[i];
    float nre = fmaf(lamL.x, cre, fmaf(-lamL.y, cim, e.x));
    float nim = fmaf(lamL.x, cim, fmaf(lamL.y, cre, e.y));
    cre = nre; cim = nim;
  }
}

// ---------------------------------------------------------------------------
// kC: fused carry fix-up + GEMM2 (bf16 MFMA).
// A-tile in LDS: [64 rows][640 cols] bf16 = exactly 80 KB, granule-swizzled:
//   logical 16B-granule g of row r stored at g' = (g&~7)|((g+r)&7).
// cols 0..511: corrected states interleaved (re,im); cols 512..639: x.
// y[64][128] = A @ Wf2, K=640.
// ---------------------------------------------------------------------------
__global__ __launch_bounds__(256, 2) void kC(
    const float* __restrict__ x, const uint* __restrict__ states,
    const float2* __restrict__ P, const float2* __restrict__ lampow2,
    const short* __restrict__ Wf2, float* __restrict__ y) {
  __shared__ short As[64 * 640];   // exactly 80 KB

  int bc = blockIdx.x;
  size_t row0 = (size_t)bc * CHUNK;
  int tid = threadIdx.x;

  // phase 1a: states fix-up -> LDS (thread = state n, loop rows)
  {
    int n = tid;
    float2 p = P[bc * N_ST + n];
    int g = n >> 2;
    int koff = (2 * n) & 7;
    for (int row = 0; row < CHUNK; ++row) {
      uint sp = states[(row0 + row) * N_ST + n];
      float2 lp = lampow2[(row + 1) * N_ST + n];
      float sr = bf2f(sp & 0xffffu) + lp.x * p.x - lp.y * p.y;
      float si = bf2f(sp >> 16) + lp.x * p.y + lp.y * p.x;
      int gp = (g & ~7) | ((g + row) & 7);
      *(uint*)(As + row * 640 + gp * 8 + koff) = pack2(sr, si);
    }
  }
  // phase 1b: x -> LDS bf16 (cols 512..639)
  {
    int kxp = tid & 63, r0 = tid >> 6;
    int k = 512 + 2 * kxp;
    int g = k >> 3, koff = k & 7;
    for (int rr = 0; rr < 16; ++rr) {
      int row = r0 * 16 + rr;
      float2 xv = *(const float2*)(x + (row0 + row) * D_IN + 2 * kxp);
      int gp = (g & ~7) | ((g + row) & 7);
      *(uint*)(As + row * 640 + gp * 8 + koff) = pack2(xv.x, xv.y);
    }
  }
  __syncthreads();

  // phase 2: MFMA. wave w -> rows 16w..16w+15; 8 col-tiles of 16.
  int lane = tid & 63, w = tid >> 6;
  int m = lane & 15, q = lane >> 4;
  int arow = 16 * w + m;

  f32x4 acc[8];
#pragma unroll
  for (int ct = 0; ct < 8; ++ct) acc[ct] = (f32x4){0.f, 0.f, 0.f, 0.f};

  for (int ks = 0; ks < 20; ++ks) {
    int g = 4 * ks + q;
    int gp = (g & ~7) | ((g + arow) & 7);
    short8 af = *(const short8*)(As + arow * 640 + gp * 8);
    const short* wbase = Wf2 + ((size_t)g * 128 + m) * 8;
#pragma unroll
    for (int ct = 0; ct < 8; ++ct) {
      short8 bf = *(const short8*)(wbase + 16 * ct * 8);
      acc[ct] = __builtin_amdgcn_mfma_f32_16x16x32_bf16(af, bf, acc[ct], 0, 0, 0);
    }
  }

#pragma unroll
  for (int ct = 0; ct < 8; ++ct) {
#pragma unroll
    for (int r = 0; r < 4; ++r) {
      y[(row0 + 16 * w + 4 * q + r) * D_OUT + 16 * ct + m] = acc[ct][r];
    }
  }
}

// ---------------------------------------------------------------------------
extern "C" void kernel_launch(void* const* d_in, const int* in_sizes, int n_in,
                              void* d_out, int out_size, void* d_ws, size_t ws_size,
                              hipStream_t stream) {
  const float* x         = (const float*)d_in[0];
  const float* nu_log    = (const float*)d_in[1];
  const float* theta_log = (const float*)d_in[2];
  const float* gamma_log = (const float*)d_in[3];
  const float* B_re      = (const float*)d_in[4];
  const float* B_im      = (const float*)d_in[5];
  const float* C_re      = (const float*)d_in[6];
  const float* C_im      = (const float*)d_in[7];
  const float* Dm        = (const float*)d_in[8];
  float* y = (float*)d_out;

  // workspace layout (4-byte units)
  char* w = (char*)d_ws;
  float2* lampow2 = (float2*)w; w += (size_t)(CHUNK + 1) * N_ST * sizeof(float2);
  short*  Wf1     = (short*)w;  w += (size_t)16 * 512 * 8 * sizeof(short);
  short*  Wf2     = (short*)w;  w += (size_t)80 * 128 * 8 * sizeof(short);
  float2* E       = (float2*)w; w += (size_t)NBLK * N_ST * sizeof(float2);
  float2* P       = (float2*)w; w += (size_t)NBLK * N_ST * sizeof(float2);
  uint*   states  = (uint*)w;   w += (size_t)BT * N_ST * sizeof(uint);

  hipLaunchKernelGGL(k0_params, dim3(1), dim3(256), 0, stream,
                     nu_log, theta_log, lampow2);
  hipLaunchKernelGGL(k0_packW, dim3(320), dim3(256), 0, stream,
                     gamma_log, B_re, B_im, C_re, C_im, Dm, Wf1, Wf2);
  hipLaunchKernelGGL(kA, dim3(NBLK), dim3(256), 0, stream,
                     x, Wf1, lampow2, states, E);
  hipLaunchKernelGGL(kB, dim3(B_SZ * N_ST / 256), dim3(256), 0, stream,
                     E, lampow2, P);
  hipLaunchKernelGGL(kC, dim3(NBLK), dim3(256), 0, stream,
                     x, states, P, lampow2, Wf2, y);
}

// Round 7
// 141.401 us; speedup vs baseline: 2.3418x; 1.1014x over previous
//
#include <hip/hip_runtime.h>
#include <math.h>

// Sizes (fixed by the problem)
#define B_SZ 8
#define T_LEN 4096
#define D_IN 128
#define D_OUT 128
#define N_ST 256
#define BT (B_SZ * T_LEN)        // 32768
#define CHUNK 64                 // scan chunk length
#define NCHUNK (T_LEN / CHUNK)   // 64 chunks per sequence
#define NBLK (B_SZ * NCHUNK)     // 512 chunk-blocks

typedef __attribute__((ext_vector_type(8))) short short8;
typedef __attribute__((ext_vector_type(4))) float f32x4;
typedef unsigned int uint;
typedef unsigned short ushort;

static __device__ __forceinline__ short f2bf(float f) {
  union { float f; uint u; } v; v.f = f;
  uint r = v.u + 0x7FFFu + ((v.u >> 16) & 1u);  // round-to-nearest-even
  return (short)(r >> 16);
}
static __device__ __forceinline__ float bf2f(uint h) {
  union { uint u; float f; } v; v.u = h << 16;
  return v.f;
}
static __device__ __forceinline__ uint pack2(float a, float b) {
  return (uint)(ushort)f2bf(a) | ((uint)(ushort)f2bf(b) << 16);
}

// ---------------------------------------------------------------------------
// k0_setup: merged setup. blk<320: R2 k0_packW body (line-identical).
// blk>=320: lampow2 row j=blk-320 (R2 k0_params float math, line-identical).
// ---------------------------------------------------------------------------
__global__ __launch_bounds__(256) void k0_setup(
    const float* __restrict__ nu_log, const float* __restrict__ theta_log,
    const float* __restrict__ gamma_log,
    const float* __restrict__ B_re, const float* __restrict__ B_im,
    const float* __restrict__ C_re, const float* __restrict__ C_im,
    const float* __restrict__ Dm,
    short* __restrict__ Wf1, short* __restrict__ Wf2,
    float2* __restrict__ lampow2) {
  int blk = blockIdx.x;
  if (blk < 320) {
    int idx = blk * 256 + threadIdx.x;
    if (idx < 16 * 512 * 8) {
      int j = idx & 7, col = (idx >> 3) & 511, kg = idx >> 12;
      int k = kg * 8 + j;
      int n = col >> 1, ri = col & 1;
      float g = expf(gamma_log[n]);
      float v = g * (ri ? B_im[n * D_IN + k] : B_re[n * D_IN + k]);
      Wf1[idx] = f2bf(v);
    }
    if (idx < 80 * 128 * 8) {
      int j = idx & 7, d = (idx >> 3) & 127, kg = idx >> 10;
      int k = kg * 8 + j;
      float v;
      if (k < 512) {
        int n = k >> 1;
        v = (k & 1) ? -C_im[d * N_ST + n] : C_re[d * N_ST + n];
      } else {
        v = Dm[d * D_IN + (k - 512)];
      }
      Wf2[idx] = f2bf(v);
    }
  } else {
    int j = blk - 320;  // 0..64
    int n = threadIdx.x;
    float e_nu = expf(nu_log[n]);
    float phase = expf(theta_log[n]);
    float r = expf(-(float)j * e_nu);
    float a = (float)j * phase;
    float2 v; v.x = r * cosf(a); v.y = r * sinf(a);
    lampow2[j * N_ST + n] = v;
  }
}

// ---------------------------------------------------------------------------
// kA: R2 VERBATIM (passed @155.7us). Fused GEMM1 (bf16 MFMA) + local chunk
// scan. Block = one (b,chunk): 64 time rows x 256 states. 4 waves.
// ---------------------------------------------------------------------------
__global__ __launch_bounds__(256, 2) void kA(
    const float* __restrict__ x, const short* __restrict__ Wf1,
    const float2* __restrict__ lampow2,
    uint* __restrict__ states, float2* __restrict__ E) {
  __shared__ short bu[64 * 520];   // row-major, +8 pad per row

  int bc = blockIdx.x;
  size_t row0 = (size_t)bc * CHUNK;
  int tid = threadIdx.x;
  int lane = tid & 63, w = tid >> 6;
  int m = lane & 15, q = lane >> 4;

  f32x4 acc[32];
#pragma unroll
  for (int ct = 0; ct < 32; ++ct) acc[ct] = (f32x4){0.f, 0.f, 0.f, 0.f};

  const float* xrow = x + (row0 + 16 * w + m) * D_IN;

  for (int ks = 0; ks < 4; ++ks) {
    float4 xa = *(const float4*)(xrow + 32 * ks + 8 * q);
    float4 xb = *(const float4*)(xrow + 32 * ks + 8 * q + 4);
    short8 af;
    af[0] = f2bf(xa.x); af[1] = f2bf(xa.y); af[2] = f2bf(xa.z); af[3] = f2bf(xa.w);
    af[4] = f2bf(xb.x); af[5] = f2bf(xb.y); af[6] = f2bf(xb.z); af[7] = f2bf(xb.w);
    const short* wbase = Wf1 + ((size_t)(4 * ks + q) * 512 + m) * 8;
#pragma unroll
    for (int ct = 0; ct < 32; ++ct) {
      short8 bf = *(const short8*)(wbase + 16 * ct * 8);
      acc[ct] = __builtin_amdgcn_mfma_f32_16x16x32_bf16(af, bf, acc[ct], 0, 0, 0);
    }
  }

  // write Bu tile to LDS (bf16). C-layout: row=4q+r, col=m within 16x16 tile.
#pragma unroll
  for (int ct = 0; ct < 32; ++ct) {
#pragma unroll
    for (int r = 0; r < 4; ++r) {
      bu[(16 * w + 4 * q + r) * 520 + 16 * ct + m] = f2bf(acc[ct][r]);
    }
  }
  __syncthreads();

  // scan: thread n owns state n
  int n = tid;
  float2 lam = lampow2[N_ST + n];  // lam^1
  float sre = 0.f, sim = 0.f;
  uint* sg = states + row0 * N_ST + n;
  for (int j = 0; j < CHUNK; ++j) {
    uint p = ((const uint*)(bu + j * 520))[n];
    float br = bf2f(p & 0xffffu), bi = bf2f(p >> 16);
    float nr = fmaf(lam.x, sre, fmaf(-lam.y, sim, br));
    float ni = fmaf(lam.x, sim, fmaf(lam.y, sre, bi));
    sre = nr; sim = ni;
    sg[(size_t)j * N_ST] = pack2(sre, sim);
  }
  float2 e; e.x = sre; e.y = sim;
  E[bc * N_ST + n] = e;
}

// ---------------------------------------------------------------------------
// kB: R2 VERBATIM. Carry scan across chunks per (b,n).
// ---------------------------------------------------------------------------
__global__ __launch_bounds__(256) void kB(
    const float2* __restrict__ E, const float2* __restrict__ lampow2,
    float2* __restrict__ P) {
  int g = blockIdx.x * 256 + threadIdx.x;  // b*N + n
  int n = g & (N_ST - 1);
  int b = g >> 8;
  float2 lamL = lampow2[CHUNK * N_ST + n];
  float cre = 0.f, cim = 0.f;
  for (int c = 0; c < NCHUNK; ++c) {
    int i = (b * NCHUNK + c) * N_ST + n;
    float2 pv; pv.x = cre; pv.y = cim;
    P[i] = pv;
    float2 e = E[i];
    float nre = fmaf(lamL.x, cre, fmaf(-lamL.y, cim, e.x));
    float nim = fmaf(lamL.x, cim, fmaf(lamL.y, cre, e.y));
    cre = nre; cim = nim;
  }
}

// ---------------------------------------------------------------------------
// kC: R2 VERBATIM. Fused carry fix-up + GEMM2 (bf16 MFMA), K=640.
// ---------------------------------------------------------------------------
__global__ __launch_bounds__(256, 2) void kC(
    const float* __restrict__ x, const uint* __restrict__ states,
    const float2* __restrict__ P, const float2* __restrict__ lampow2,
    const short* __restrict__ Wf2, float* __restrict__ y) {
  __shared__ short As[64 * 640];   // exactly 80 KB

  int bc = blockIdx.x;
  size_t row0 = (size_t)bc * CHUNK;
  int tid = threadIdx.x;

  // phase 1a: states fix-up -> LDS (thread = state n, loop rows)
  {
    int n = tid;
    float2 p = P[bc * N_ST + n];
    int g = n >> 2;
    int koff = (2 * n) & 7;
    for (int row = 0; row < CHUNK; ++row) {
      uint sp = states[(row0 + row) * N_ST + n];
      float2 lp = lampow2[(row + 1) * N_ST + n];
      float sr = bf2f(sp & 0xffffu) + lp.x * p.x - lp.y * p.y;
      float si = bf2f(sp >> 16) + lp.x * p.y + lp.y * p.x;
      int gp = (g & ~7) | ((g + row) & 7);
      *(uint*)(As + row * 640 + gp * 8 + koff) = pack2(sr, si);
    }
  }
  // phase 1b: x -> LDS bf16 (cols 512..639)
  {
    int kxp = tid & 63, r0 = tid >> 6;
    int k = 512 + 2 * kxp;
    int g = k >> 3, koff = k & 7;
    for (int rr = 0; rr < 16; ++rr) {
      int row = r0 * 16 + rr;
      float2 xv = *(const float2*)(x + (row0 + row) * D_IN + 2 * kxp);
      int gp = (g & ~7) | ((g + row) & 7);
      *(uint*)(As + row * 640 + gp * 8 + koff) = pack2(xv.x, xv.y);
    }
  }
  __syncthreads();

  // phase 2: MFMA. wave w -> rows 16w..16w+15; 8 col-tiles of 16.
  int lane = tid & 63, w = tid >> 6;
  int m = lane & 15, q = lane >> 4;
  int arow = 16 * w + m;

  f32x4 acc[8];
#pragma unroll
  for (int ct = 0; ct < 8; ++ct) acc[ct] = (f32x4){0.f, 0.f, 0.f, 0.f};

  for (int ks = 0; ks < 20; ++ks) {
    int g = 4 * ks + q;
    int gp = (g & ~7) | ((g + arow) & 7);
    short8 af = *(const short8*)(As + arow * 640 + gp * 8);
    const short* wbase = Wf2 + ((size_t)g * 128 + m) * 8;
#pragma unroll
    for (int ct = 0; ct < 8; ++ct) {
      short8 bf = *(const short8*)(wbase + 16 * ct * 8);
      acc[ct] = __builtin_amdgcn_mfma_f32_16x16x32_bf16(af, bf, acc[ct], 0, 0, 0);
    }
  }

#pragma unroll
  for (int ct = 0; ct < 8; ++ct) {
#pragma unroll
    for (int r = 0; r < 4; ++r) {
      y[(row0 + 16 * w + 4 * q + r) * D_OUT + 16 * ct + m] = acc[ct][r];
    }
  }
}

// ---------------------------------------------------------------------------
extern "C" void kernel_launch(void* const* d_in, const int* in_sizes, int n_in,
                              void* d_out, int out_size, void* d_ws, size_t ws_size,
                              hipStream_t stream) {
  const float* x         = (const float*)d_in[0];
  const float* nu_log    = (const float*)d_in[1];
  const float* theta_log = (const float*)d_in[2];
  const float* gamma_log = (const float*)d_in[3];
  const float* B_re      = (const float*)d_in[4];
  const float* B_im      = (const float*)d_in[5];
  const float* C_re      = (const float*)d_in[6];
  const float* C_im      = (const float*)d_in[7];
  const float* Dm        = (const float*)d_in[8];
  float* y = (float*)d_out;

  // workspace layout (R2 order)
  char* wp = (char*)d_ws;
  float2* lampow2 = (float2*)wp; wp += (size_t)(CHUNK + 1) * N_ST * sizeof(float2);
  short*  Wf1     = (short*)wp;  wp += (size_t)16 * 512 * 8 * sizeof(short);
  short*  Wf2     = (short*)wp;  wp += (size_t)80 * 128 * 8 * sizeof(short);
  float2* E       = (float2*)wp; wp += (size_t)NBLK * N_ST * sizeof(float2);
  float2* P       = (float2*)wp; wp += (size_t)NBLK * N_ST * sizeof(float2);
  uint*   states  = (uint*)wp;   wp += (size_t)BT * N_ST * sizeof(uint);

  hipLaunchKernelGGL(k0_setup, dim3(385), dim3(256), 0, stream,
                     nu_log, theta_log, gamma_log, B_re, B_im, C_re, C_im, Dm,
                     Wf1, Wf2, lampow2);
  hipLaunchKernelGGL(kA, dim3(NBLK), dim3(256), 0, stream,
                     x, Wf1, lampow2, states, E);
  hipLaunchKernelGGL(kB, dim3(B_SZ * N_ST / 256), dim3(256), 0, stream,
                     E, lampow2, P);
  hipLaunchKernelGGL(kC, dim3(NBLK), dim3(256), 0, stream,
                     x, states, P, lampow2, Wf2, y);
}